// Round 5
// baseline (196.086 us; speedup 1.0000x reference)
//
#include <hip/hip_runtime.h>
#include <hip/hip_bf16.h>

typedef __attribute__((ext_vector_type(4))) float f32x4;
typedef __attribute__((ext_vector_type(8))) short bf16x8;
typedef __attribute__((ext_vector_type(8))) unsigned short u16x8;
typedef unsigned short u16;

#define DEV static __device__ __forceinline__

DEV u16 f2bf(float f) {
    union { float f; unsigned int u; } v; v.f = f;
    unsigned int r = v.u + 0x7FFFu + ((v.u >> 16) & 1u);
    return (u16)(r >> 16);
}

DEV unsigned int cvt_pk(float lo, float hi) {
    unsigned int r;
    asm("v_cvt_pk_bf16_f32 %0, %1, %2" : "=v"(r) : "v"(lo), "v"(hi));
    return r;
}

DEV void async16(const void* g, void* l) {
    __builtin_amdgcn_global_load_lds((const __attribute__((address_space(1))) unsigned int*)g,
                                     (__attribute__((address_space(3))) unsigned int*)l, 16, 0, 0);
}

// ---------------- fused f32 -> bf16 convert + exp-mask precompute ----------------
__global__ void cvt_all(const float4* __restrict__ x, const float4* __restrict__ wq,
                        const float4* __restrict__ wk, const float4* __restrict__ wv,
                        ushort4* __restrict__ xb, ushort4* __restrict__ wb,
                        const float* __restrict__ mask, float* __restrict__ em) {
    int bid = blockIdx.x;
    if (bid >= 11264) {
        // em[b,s] = exp(mask[b,s]) = exp2(mask * log2e); 4*2048 elements
        int i = (bid - 11264) * 256 + threadIdx.x;
        em[i] = __builtin_amdgcn_exp2f(mask[i] * 1.44269504088896340736f);
        return;
    }
    const float4* s;
    ushort4* d;
    int i;
    if (bid < 8192) {
        s = x; d = xb; i = bid * 256 + threadIdx.x;
    } else {
        int r = bid - 8192;
        int wsel = r >> 10;
        s = (wsel == 0) ? wq : (wsel == 1) ? wk : wv;
        d = wb + (size_t)wsel * 262144;
        i = (r & 1023) * 256 + threadIdx.x;
    }
    float4 v = s[i];
    ushort4 o;
    o.x = f2bf(v.x); o.y = f2bf(v.y); o.z = f2bf(v.z); o.w = f2bf(v.w);
    d[i] = o;
}

// ---------------- QKV projection GEMM (double-buffered, prefetch, 1 barrier/iter) ----------------
// p=0,1 -> Q,K scattered to [B,H,S,64]; p=2 -> V transposed [B,H,64,S], pre-scaled by em[b,s]
__launch_bounds__(256, 2)
__global__ void qkv_gemm(const u16* __restrict__ xb, const u16* __restrict__ wb,
                         const float* __restrict__ bq, const float* __restrict__ bk,
                         const float* __restrict__ bv, const float* __restrict__ em,
                         u16* __restrict__ Qb, u16* __restrict__ Kb, u16* __restrict__ Vtb) {
    __shared__ u16 Al[2][128 * 64];
    __shared__ u16 Bl[2][128 * 64];
    const int t = threadIdx.x, ln = t & 63, w = t >> 6;
    const int wr = w >> 1, wc = w & 1;
    const int m0 = blockIdx.x * 128, e0 = blockIdx.y * 128, p = blockIdx.z;
    const u16* Wp = wb + (size_t)p * 1048576;
    const float* bias = (p == 0) ? bq : (p == 1) ? bk : bv;

    const int srow = t >> 3, scol = (t & 7) * 8;

    f32x4 acc[4][4];
#pragma unroll
    for (int i = 0; i < 4; i++)
#pragma unroll
        for (int j = 0; j < 4; j++) acc[i][j] = (f32x4){0.f, 0.f, 0.f, 0.f};

#define G_STAGE(buf, kk)                                                              \
    {                                                                                 \
        _Pragma("unroll")                                                             \
        for (int c = 0; c < 4; c++) {                                                 \
            int r = c * 32 + srow;                                                    \
            async16(&xb[(size_t)(m0 + r) * 1024 + (kk) + scol], &Al[buf][r * 64 + scol]); \
            async16(&Wp[(size_t)(e0 + r) * 1024 + (kk) + scol], &Bl[buf][r * 64 + scol]); \
        }                                                                             \
    }

    G_STAGE(0, 0);
    __syncthreads();
    int cur = 0;
    for (int kt = 0; kt < 16; kt++) {
        if (kt < 15) G_STAGE(cur ^ 1, (kt + 1) * 64);
#pragma unroll
        for (int kc = 0; kc < 2; kc++) {
            bf16x8 a[4], bb[4];
#pragma unroll
            for (int mf = 0; mf < 4; mf++)
                a[mf] = *(const bf16x8*)&Al[cur][(wr * 64 + mf * 16 + (ln & 15)) * 64 + kc * 32 + (ln >> 4) * 8];
#pragma unroll
            for (int nf = 0; nf < 4; nf++)
                bb[nf] = *(const bf16x8*)&Bl[cur][(wc * 64 + nf * 16 + (ln & 15)) * 64 + kc * 32 + (ln >> 4) * 8];
            __builtin_amdgcn_s_setprio(1);
#pragma unroll
            for (int mf = 0; mf < 4; mf++)
#pragma unroll
                for (int nf = 0; nf < 4; nf++)
                    acc[mf][nf] = __builtin_amdgcn_mfma_f32_16x16x32_bf16(a[mf], bb[nf], acc[mf][nf], 0, 0, 0);
            __builtin_amdgcn_s_setprio(0);
        }
        __syncthreads();
        cur ^= 1;
    }
#undef G_STAGE

    const int q16 = ln & 15, g = ln >> 4;
    if (p == 2) {
        // V written transposed and pre-scaled by em: Vt[((b*16+h)*64+hd)*2048 + s]
#pragma unroll
        for (int nf = 0; nf < 4; nf++) {
            int e = e0 + wc * 64 + nf * 16 + q16;
            float bias_v = bias[e];
            int h = e >> 6, hd = e & 63;
#pragma unroll
            for (int mf = 0; mf < 4; mf++) {
                int m = m0 + wr * 64 + mf * 16 + g * 4;
                int b = m >> 11, s = m & 2047;
                f32x4 emv = *(const f32x4*)&em[b * 2048 + s];
                ushort4 pk;
                pk.x = f2bf((acc[mf][nf][0] + bias_v) * emv[0]);
                pk.y = f2bf((acc[mf][nf][1] + bias_v) * emv[1]);
                pk.z = f2bf((acc[mf][nf][2] + bias_v) * emv[2]);
                pk.w = f2bf((acc[mf][nf][3] + bias_v) * emv[3]);
                *(ushort4*)&Vtb[((size_t)((b * 16 + h) * 64 + hd)) * 2048 + s] = pk;
            }
        }
    } else {
        u16* out = (p == 0) ? Qb : Kb;
#pragma unroll
        for (int nf = 0; nf < 4; nf++) {
            int e = e0 + wc * 64 + nf * 16 + q16;
            float bias_v = bias[e];
            int h = e >> 6, hd = e & 63;
#pragma unroll
            for (int mf = 0; mf < 4; mf++) {
#pragma unroll
                for (int r = 0; r < 4; r++) {
                    int m = m0 + wr * 64 + mf * 16 + g * 4 + r;
                    int b = m >> 11, s = m & 2047;
                    out[((size_t)(b * 16 + h) * 2048 + s) * 64 + hd] = f2bf(acc[mf][nf][r] + bias_v);
                }
            }
        }
    }
}

// ---------------- fused flash attention ----------------
// dbuf K/V + prefetch, 1 barrier/iter; per-mf sequential softmax/PV (Pl = 2KB/wave);
// mask folded multiplicatively into V (em) and the l-sum.
__launch_bounds__(256, 4)
__global__ void attn_kernel(const u16* __restrict__ Q, const u16* __restrict__ K,
                            const u16* __restrict__ Vt, const float* __restrict__ em,
                            float* __restrict__ out) {
    __shared__ u16 Kl[2][64 * 64];
    __shared__ u16 Vl[2][64 * 64];
    __shared__ u16 Pl[4][16 * 64];
    const int t = threadIdx.x, ln = t & 63, w = t >> 6;
    const int q16 = ln & 15, g = ln >> 4;

    // bijective XCD swizzle: 1024 blocks = 8 XCDs x 128
    const int bid0 = blockIdx.x;
    const int swz = (bid0 & 7) * 128 + (bid0 >> 3);
    const int qbi = swz & 15, bh = swz >> 4;
    const int b = bh >> 4, h = bh & 15;
    const int qr = qbi * 128 + w * 32;
    const size_t base = (size_t)bh * 2048 * 64;
    const float L2E = 1.44269504088896340736f;
    const float C1 = 0.125f * L2E;

    // Q fragments (B-operand of swapped QK^T)
    bf16x8 aq[2][2];
#pragma unroll
    for (int mf = 0; mf < 2; mf++)
#pragma unroll
        for (int dc = 0; dc < 2; dc++)
            aq[mf][dc] = *(const bf16x8*)&Q[base + (size_t)(qr + mf * 16 + q16) * 64 + dc * 32 + g * 8];

    const int row0 = t >> 3, row1 = 32 + (t >> 3);
    const int sc = (t & 7) ^ (row0 & 7);

    const int swz0 = (g ^ (q16 & 7)) * 8;
    const int swz1 = ((g ^ 4) ^ (q16 & 7)) * 8;

#define A_STAGE(buf, kk)                                                              \
    {                                                                                 \
        async16(&K[base + (size_t)((kk) + row0) * 64 + sc * 8], &Kl[buf][t * 8]);     \
        async16(&K[base + (size_t)((kk) + row1) * 64 + sc * 8], &Kl[buf][2048 + t * 8]); \
        async16(&Vt[base + (size_t)row0 * 2048 + (kk) + sc * 8], &Vl[buf][t * 8]);    \
        async16(&Vt[base + (size_t)row1 * 2048 + (kk) + sc * 8], &Vl[buf][2048 + t * 8]); \
    }

    f32x4 accT[4][2];
    f32x4 lacc[2];
#pragma unroll
    for (int nf = 0; nf < 4; nf++)
#pragma unroll
        for (int mf = 0; mf < 2; mf++) accT[nf][mf] = (f32x4){0.f, 0.f, 0.f, 0.f};
    lacc[0] = (f32x4){0.f, 0.f, 0.f, 0.f};
    lacc[1] = (f32x4){0.f, 0.f, 0.f, 0.f};

    A_STAGE(0, 0);
    __syncthreads();
    int cur = 0;

    for (int kt = 0; kt < 32; kt++) {
        const int k0 = kt * 64;
        if (kt < 31) A_STAGE(cur ^ 1, k0 + 64);

        // em for this lane's k values (k = k0 + kf*16 + g*4 + r)
        f32x4 em4[4];
#pragma unroll
        for (int kf = 0; kf < 4; kf++)
            em4[kf] = *(const f32x4*)&em[b * 2048 + k0 + kf * 16 + g * 4];

        // K fragments (shared by both q-halves)
        bf16x8 ka[4][2];
#pragma unroll
        for (int kf = 0; kf < 4; kf++) {
            ka[kf][0] = *(const bf16x8*)&Kl[cur][(kf * 16 + q16) * 64 + swz0];
            ka[kf][1] = *(const bf16x8*)&Kl[cur][(kf * 16 + q16) * 64 + swz1];
        }

#pragma unroll
        for (int mf = 0; mf < 2; mf++) {
            // S^T = K·Q^T for q-half mf: lane q=q16, k = kf*16+g*4+r
            f32x4 st[4];
            __builtin_amdgcn_s_setprio(1);
#pragma unroll
            for (int kf = 0; kf < 4; kf++) {
                f32x4 z = (f32x4){0.f, 0.f, 0.f, 0.f};
                z = __builtin_amdgcn_mfma_f32_16x16x32_bf16(ka[kf][0], aq[mf][0], z, 0, 0, 0);
                z = __builtin_amdgcn_mfma_f32_16x16x32_bf16(ka[kf][1], aq[mf][1], z, 0, 0, 0);
                st[kf] = z;
            }
            __builtin_amdgcn_s_setprio(0);

            // p = exp2(score * 0.125 * log2e); mask folded into V/l via em
#pragma unroll
            for (int kf = 0; kf < 4; kf++)
#pragma unroll
                for (int r = 0; r < 4; r++)
                    st[kf][r] = __builtin_amdgcn_exp2f(st[kf][r] * C1);
#pragma unroll
            for (int kf = 0; kf < 4; kf++)
                lacc[mf] += st[kf] * em4[kf];

            // P^T -> Pl (16 q-rows per wave, reused across mf; in-order DS pipe)
#pragma unroll
            for (int kf = 0; kf < 4; kf++) {
                uint2 pk;
                pk.x = cvt_pk(st[kf][0], st[kf][1]);
                pk.y = cvt_pk(st[kf][2], st[kf][3]);
                *(uint2*)&Pl[w][q16 * 64 + ((kf * 16 + g * 4) ^ ((q16 & 7) << 3))] = pk;
            }

            // ctx^T += V'^T · P^T  (V' already scaled by em)
            __builtin_amdgcn_s_setprio(1);
#pragma unroll
            for (int kc = 0; kc < 2; kc++) {
                const int so = kc ? swz1 : swz0;
                bf16x8 pa = *(const bf16x8*)&Pl[w][q16 * 64 + so];
                bf16x8 bv4[4];
#pragma unroll
                for (int nf = 0; nf < 4; nf++)
                    bv4[nf] = *(const bf16x8*)&Vl[cur][(nf * 16 + q16) * 64 + so];
#pragma unroll
                for (int nf = 0; nf < 4; nf++)
                    accT[nf][mf] = __builtin_amdgcn_mfma_f32_16x16x32_bf16(bv4[nf], pa, accT[nf][mf], 0, 0, 0);
            }
            __builtin_amdgcn_s_setprio(0);
        }

        __syncthreads();
        cur ^= 1;
    }
#undef A_STAGE

#pragma unroll
    for (int mf = 0; mf < 2; mf++) {
        float l = (lacc[mf][0] + lacc[mf][1]) + (lacc[mf][2] + lacc[mf][3]);
        l += __shfl_xor(l, 16);
        l += __shfl_xor(l, 32);
        float inv = 1.0f / l;
        int q = qr + mf * 16 + q16;
#pragma unroll
        for (int nf = 0; nf < 4; nf++) {
            f32x4 o = accT[nf][mf] * inv;
            *(f32x4*)&out[((size_t)(b * 2048 + q)) * 1024 + h * 64 + nf * 16 + g * 4] = o;
        }
    }
}

extern "C" void kernel_launch(void* const* d_in, const int* in_sizes, int n_in,
                              void* d_out, int out_size, void* d_ws, size_t ws_size,
                              hipStream_t stream) {
    const float* x    = (const float*)d_in[0];
    const float* mask = (const float*)d_in[1];
    const float* Wq   = (const float*)d_in[2];
    const float* bq   = (const float*)d_in[3];
    const float* Wk   = (const float*)d_in[4];
    const float* bk   = (const float*)d_in[5];
    const float* Wv   = (const float*)d_in[6];
    const float* bv   = (const float*)d_in[7];
    float* out = (float*)d_out;

    char* ws = (char*)d_ws;
    if (ws_size < (size_t)73433088) return;
    u16* xb   = (u16*)(ws);
    u16* wb   = (u16*)(ws + 16777216);
    u16* Qb   = (u16*)(ws + 23068672);
    u16* Kb   = (u16*)(ws + 39845888);
    u16* Vtb  = (u16*)(ws + 56623104);
    float* em = (float*)(ws + 73400320);

    cvt_all<<<11296, 256, 0, stream>>>((const float4*)x, (const float4*)Wq, (const float4*)Wk,
                                       (const float4*)Wv, (ushort4*)xb, (ushort4*)wb, mask, em);
    qkv_gemm<<<dim3(64, 8, 3), 256, 0, stream>>>(xb, wb, bq, bk, bv, em, Qb, Kb, Vtb);
    attn_kernel<<<1024, 256, 0, stream>>>(Qb, Kb, Vtb, em, out);
}

// Round 6
// 169.594 us; speedup vs baseline: 1.1562x; 1.1562x over previous
//
#include <hip/hip_runtime.h>
#include <hip/hip_bf16.h>

typedef __attribute__((ext_vector_type(4))) float f32x4;
typedef __attribute__((ext_vector_type(8))) short bf16x8;
typedef __attribute__((ext_vector_type(8))) unsigned short u16x8;
typedef unsigned short u16;

#define DEV static __device__ __forceinline__

DEV u16 f2bf(float f) {
    union { float f; unsigned int u; } v; v.f = f;
    unsigned int r = v.u + 0x7FFFu + ((v.u >> 16) & 1u);
    return (u16)(r >> 16);
}

DEV unsigned int cvt_pk(float lo, float hi) {
    unsigned int r;
    asm("v_cvt_pk_bf16_f32 %0, %1, %2" : "=v"(r) : "v"(lo), "v"(hi));
    return r;
}

DEV void async16(const void* g, void* l) {
    __builtin_amdgcn_global_load_lds((const __attribute__((address_space(1))) unsigned int*)g,
                                     (__attribute__((address_space(3))) unsigned int*)l, 16, 0, 0);
}

// ---------------- fused f32 -> bf16 convert + exp-mask precompute ----------------
__global__ void cvt_all(const float4* __restrict__ x, const float4* __restrict__ wq,
                        const float4* __restrict__ wk, const float4* __restrict__ wv,
                        ushort4* __restrict__ xb, ushort4* __restrict__ wb,
                        const float* __restrict__ mask, float* __restrict__ em) {
    int bid = blockIdx.x;
    if (bid >= 11264) {
        int i = (bid - 11264) * 256 + threadIdx.x;
        em[i] = __builtin_amdgcn_exp2f(mask[i] * 1.44269504088896340736f);
        return;
    }
    const float4* s;
    ushort4* d;
    int i;
    if (bid < 8192) {
        s = x; d = xb; i = bid * 256 + threadIdx.x;
    } else {
        int r = bid - 8192;
        int wsel = r >> 10;
        s = (wsel == 0) ? wq : (wsel == 1) ? wk : wv;
        d = wb + (size_t)wsel * 262144;
        i = (r & 1023) * 256 + threadIdx.x;
    }
    float4 v = s[i];
    ushort4 o;
    o.x = f2bf(v.x); o.y = f2bf(v.y); o.z = f2bf(v.z); o.w = f2bf(v.w);
    d[i] = o;
}

// ---------------- QKV projection GEMM (double-buffered, prefetch, 1 barrier/iter) ----------------
// p=0,1 -> Q,K scattered to [B,H,S,64]; p=2 -> V transposed [B,H,64,S], pre-scaled by em[b,s]
__launch_bounds__(256, 2)
__global__ void qkv_gemm(const u16* __restrict__ xb, const u16* __restrict__ wb,
                         const float* __restrict__ bq, const float* __restrict__ bk,
                         const float* __restrict__ bv, const float* __restrict__ em,
                         u16* __restrict__ Qb, u16* __restrict__ Kb, u16* __restrict__ Vtb) {
    __shared__ u16 Al[2][128 * 64];
    __shared__ u16 Bl[2][128 * 64];
    const int t = threadIdx.x, ln = t & 63, w = t >> 6;
    const int wr = w >> 1, wc = w & 1;
    const int m0 = blockIdx.x * 128, e0 = blockIdx.y * 128, p = blockIdx.z;
    const u16* Wp = wb + (size_t)p * 1048576;
    const float* bias = (p == 0) ? bq : (p == 1) ? bk : bv;

    const int srow = t >> 3, scol = (t & 7) * 8;

    f32x4 acc[4][4];
#pragma unroll
    for (int i = 0; i < 4; i++)
#pragma unroll
        for (int j = 0; j < 4; j++) acc[i][j] = (f32x4){0.f, 0.f, 0.f, 0.f};

#define G_STAGE(buf, kk)                                                              \
    {                                                                                 \
        _Pragma("unroll")                                                             \
        for (int c = 0; c < 4; c++) {                                                 \
            int r = c * 32 + srow;                                                    \
            async16(&xb[(size_t)(m0 + r) * 1024 + (kk) + scol], &Al[buf][r * 64 + scol]); \
            async16(&Wp[(size_t)(e0 + r) * 1024 + (kk) + scol], &Bl[buf][r * 64 + scol]); \
        }                                                                             \
    }

    G_STAGE(0, 0);
    __syncthreads();
    int cur = 0;
    for (int kt = 0; kt < 16; kt++) {
        if (kt < 15) G_STAGE(cur ^ 1, (kt + 1) * 64);
#pragma unroll
        for (int kc = 0; kc < 2; kc++) {
            bf16x8 a[4], bb[4];
#pragma unroll
            for (int mf = 0; mf < 4; mf++)
                a[mf] = *(const bf16x8*)&Al[cur][(wr * 64 + mf * 16 + (ln & 15)) * 64 + kc * 32 + (ln >> 4) * 8];
#pragma unroll
            for (int nf = 0; nf < 4; nf++)
                bb[nf] = *(const bf16x8*)&Bl[cur][(wc * 64 + nf * 16 + (ln & 15)) * 64 + kc * 32 + (ln >> 4) * 8];
            __builtin_amdgcn_s_setprio(1);
#pragma unroll
            for (int mf = 0; mf < 4; mf++)
#pragma unroll
                for (int nf = 0; nf < 4; nf++)
                    acc[mf][nf] = __builtin_amdgcn_mfma_f32_16x16x32_bf16(a[mf], bb[nf], acc[mf][nf], 0, 0, 0);
            __builtin_amdgcn_s_setprio(0);
        }
        __syncthreads();
        cur ^= 1;
    }
#undef G_STAGE

    const int q16 = ln & 15, g = ln >> 4;
    if (p == 2) {
#pragma unroll
        for (int nf = 0; nf < 4; nf++) {
            int e = e0 + wc * 64 + nf * 16 + q16;
            float bias_v = bias[e];
            int h = e >> 6, hd = e & 63;
#pragma unroll
            for (int mf = 0; mf < 4; mf++) {
                int m = m0 + wr * 64 + mf * 16 + g * 4;
                int b = m >> 11, s = m & 2047;
                f32x4 emv = *(const f32x4*)&em[b * 2048 + s];
                ushort4 pk;
                pk.x = f2bf((acc[mf][nf][0] + bias_v) * emv[0]);
                pk.y = f2bf((acc[mf][nf][1] + bias_v) * emv[1]);
                pk.z = f2bf((acc[mf][nf][2] + bias_v) * emv[2]);
                pk.w = f2bf((acc[mf][nf][3] + bias_v) * emv[3]);
                *(ushort4*)&Vtb[((size_t)((b * 16 + h) * 64 + hd)) * 2048 + s] = pk;
            }
        }
    } else {
        u16* out = (p == 0) ? Qb : Kb;
#pragma unroll
        for (int nf = 0; nf < 4; nf++) {
            int e = e0 + wc * 64 + nf * 16 + q16;
            float bias_v = bias[e];
            int h = e >> 6, hd = e & 63;
#pragma unroll
            for (int mf = 0; mf < 4; mf++) {
#pragma unroll
                for (int r = 0; r < 4; r++) {
                    int m = m0 + wr * 64 + mf * 16 + g * 4 + r;
                    int b = m >> 11, s = m & 2047;
                    out[((size_t)(b * 16 + h) * 2048 + s) * 64 + hd] = f2bf(acc[mf][nf][r] + bias_v);
                }
            }
        }
    }
}

// ---------------- fused flash attention ----------------
// 64 q-rows per wave (4 mf-tiles): each K/V LDS fragment read feeds 4 MFMAs.
// dbuf K/V + prefetch, 1 barrier/iter; mask folded into V (em) and the l-sum.
__launch_bounds__(256, 2)
__global__ void attn_kernel(const u16* __restrict__ Q, const u16* __restrict__ K,
                            const u16* __restrict__ Vt, const float* __restrict__ em,
                            float* __restrict__ out) {
    __shared__ u16 Kl[2][64 * 64];
    __shared__ u16 Vl[2][64 * 64];
    __shared__ u16 Pl[4][64 * 64];
    const int t = threadIdx.x, ln = t & 63, w = t >> 6;
    const int q16 = ln & 15, g = ln >> 4;

    // bijective XCD swizzle: 512 blocks = 8 XCDs x 64
    const int bid0 = blockIdx.x;
    const int swz = (bid0 & 7) * 64 + (bid0 >> 3);
    const int qbi = swz & 7, bh = swz >> 3;
    const int b = bh >> 4, h = bh & 15;
    const int qr = qbi * 256 + w * 64;
    const size_t base = (size_t)bh * 2048 * 64;
    const float L2E = 1.44269504088896340736f;
    const float C1 = 0.125f * L2E;

    // Q fragments (B-operand of swapped QK^T), 4 q-tiles of 16
    bf16x8 aq[4][2];
#pragma unroll
    for (int mf = 0; mf < 4; mf++)
#pragma unroll
        for (int dc = 0; dc < 2; dc++)
            aq[mf][dc] = *(const bf16x8*)&Q[base + (size_t)(qr + mf * 16 + q16) * 64 + dc * 32 + g * 8];

    const int row0 = t >> 3, row1 = 32 + (t >> 3);
    const int sc = (t & 7) ^ (row0 & 7);

    // chunk-swizzled fragment offsets: chunk c = kc*4+g stored at (c ^ (q16&7))
    const int swz0 = (g ^ (q16 & 7)) * 8;
    const int swz1 = ((g ^ 4) ^ (q16 & 7)) * 8;

#define A_STAGE(buf, kk)                                                              \
    {                                                                                 \
        async16(&K[base + (size_t)((kk) + row0) * 64 + sc * 8], &Kl[buf][t * 8]);     \
        async16(&K[base + (size_t)((kk) + row1) * 64 + sc * 8], &Kl[buf][2048 + t * 8]); \
        async16(&Vt[base + (size_t)row0 * 2048 + (kk) + sc * 8], &Vl[buf][t * 8]);    \
        async16(&Vt[base + (size_t)row1 * 2048 + (kk) + sc * 8], &Vl[buf][2048 + t * 8]); \
    }

    f32x4 accT[4][4];   // [d-tile nf][q-tile mf]; lane: q=q16, d=nf*16+g*4+r
    f32x4 lacc[4];      // per-lane partial denominators per q-tile
#pragma unroll
    for (int nf = 0; nf < 4; nf++)
#pragma unroll
        for (int mf = 0; mf < 4; mf++) accT[nf][mf] = (f32x4){0.f, 0.f, 0.f, 0.f};
#pragma unroll
    for (int mf = 0; mf < 4; mf++) lacc[mf] = (f32x4){0.f, 0.f, 0.f, 0.f};

    A_STAGE(0, 0);
    __syncthreads();
    int cur = 0;

    for (int kt = 0; kt < 32; kt++) {
        const int k0 = kt * 64;
        if (kt < 31) A_STAGE(cur ^ 1, k0 + 64);

        // em for this lane's k values (k = k0 + kf*16 + g*4 + r)
        f32x4 em4[4];
#pragma unroll
        for (int kf = 0; kf < 4; kf++)
            em4[kf] = *(const f32x4*)&em[b * 2048 + k0 + kf * 16 + g * 4];

        // K fragments (reused by all 4 q-tiles)
        bf16x8 ka[4][2];
#pragma unroll
        for (int kf = 0; kf < 4; kf++) {
            ka[kf][0] = *(const bf16x8*)&Kl[cur][(kf * 16 + q16) * 64 + swz0];
            ka[kf][1] = *(const bf16x8*)&Kl[cur][(kf * 16 + q16) * 64 + swz1];
        }

        // QK^T + softmax + P-write, per q-tile
#pragma unroll
        for (int mf = 0; mf < 4; mf++) {
            f32x4 st[4];
            __builtin_amdgcn_s_setprio(1);
#pragma unroll
            for (int kf = 0; kf < 4; kf++) {
                f32x4 z = (f32x4){0.f, 0.f, 0.f, 0.f};
                z = __builtin_amdgcn_mfma_f32_16x16x32_bf16(ka[kf][0], aq[mf][0], z, 0, 0, 0);
                z = __builtin_amdgcn_mfma_f32_16x16x32_bf16(ka[kf][1], aq[mf][1], z, 0, 0, 0);
                st[kf] = z;
            }
            __builtin_amdgcn_s_setprio(0);
#pragma unroll
            for (int kf = 0; kf < 4; kf++)
#pragma unroll
                for (int r = 0; r < 4; r++)
                    st[kf][r] = __builtin_amdgcn_exp2f(st[kf][r] * C1);
#pragma unroll
            for (int kf = 0; kf < 4; kf++)
                lacc[mf] += st[kf] * em4[kf];
#pragma unroll
            for (int kf = 0; kf < 4; kf++) {
                uint2 pk;
                pk.x = cvt_pk(st[kf][0], st[kf][1]);
                pk.y = cvt_pk(st[kf][2], st[kf][3]);
                *(uint2*)&Pl[w][(mf * 16 + q16) * 64 + ((kf * 16 + g * 4) ^ ((q16 & 7) << 3))] = pk;
            }
        }

        // ctx^T += V'^T · P^T  (V' pre-scaled by em); V frags reused by 4 q-tiles
        __builtin_amdgcn_s_setprio(1);
#pragma unroll
        for (int kc = 0; kc < 2; kc++) {
            const int so = kc ? swz1 : swz0;
            bf16x8 bv4[4], pa[4];
#pragma unroll
            for (int nf = 0; nf < 4; nf++)
                bv4[nf] = *(const bf16x8*)&Vl[cur][(nf * 16 + q16) * 64 + so];
#pragma unroll
            for (int mf = 0; mf < 4; mf++)
                pa[mf] = *(const bf16x8*)&Pl[w][(mf * 16 + q16) * 64 + so];
#pragma unroll
            for (int nf = 0; nf < 4; nf++)
#pragma unroll
                for (int mf = 0; mf < 4; mf++)
                    accT[nf][mf] = __builtin_amdgcn_mfma_f32_16x16x32_bf16(bv4[nf], pa[mf], accT[nf][mf], 0, 0, 0);
        }
        __builtin_amdgcn_s_setprio(0);

        __syncthreads();
        cur ^= 1;
    }
#undef A_STAGE

#pragma unroll
    for (int mf = 0; mf < 4; mf++) {
        float l = (lacc[mf][0] + lacc[mf][1]) + (lacc[mf][2] + lacc[mf][3]);
        l += __shfl_xor(l, 16);
        l += __shfl_xor(l, 32);
        float inv = 1.0f / l;
        int q = qr + mf * 16 + q16;
#pragma unroll
        for (int nf = 0; nf < 4; nf++) {
            f32x4 o = accT[nf][mf] * inv;
            *(f32x4*)&out[((size_t)(b * 2048 + q)) * 1024 + h * 64 + nf * 16 + g * 4] = o;
        }
    }
}

extern "C" void kernel_launch(void* const* d_in, const int* in_sizes, int n_in,
                              void* d_out, int out_size, void* d_ws, size_t ws_size,
                              hipStream_t stream) {
    const float* x    = (const float*)d_in[0];
    const float* mask = (const float*)d_in[1];
    const float* Wq   = (const float*)d_in[2];
    const float* bq   = (const float*)d_in[3];
    const float* Wk   = (const float*)d_in[4];
    const float* bk   = (const float*)d_in[5];
    const float* Wv   = (const float*)d_in[6];
    const float* bv   = (const float*)d_in[7];
    float* out = (float*)d_out;

    char* ws = (char*)d_ws;
    if (ws_size < (size_t)73433088) return;
    u16* xb   = (u16*)(ws);
    u16* wb   = (u16*)(ws + 16777216);
    u16* Qb   = (u16*)(ws + 23068672);
    u16* Kb   = (u16*)(ws + 39845888);
    u16* Vtb  = (u16*)(ws + 56623104);
    float* em = (float*)(ws + 73400320);

    cvt_all<<<11296, 256, 0, stream>>>((const float4*)x, (const float4*)Wq, (const float4*)Wk,
                                       (const float4*)Wv, (ushort4*)xb, (ushort4*)wb, mask, em);
    qkv_gemm<<<dim3(64, 8, 3), 256, 0, stream>>>(xb, wb, bq, bk, bv, em, Qb, Kb, Vtb);
    attn_kernel<<<512, 256, 0, stream>>>(Qb, Kb, Vtb, em, out);
}